// Round 4
// baseline (248.938 us; speedup 1.0000x reference)
//
#include <hip/hip_runtime.h>

constexpr int S = 4096, M = 512, E = 16, CC = 128;
constexpr int H1 = 500, H2 = 500, H3 = 2000;

typedef short short8 __attribute__((ext_vector_type(8)));
typedef float f32x16 __attribute__((ext_vector_type(16)));

// select = x @ Wr^T + noise   (one wave per token)
__global__ void k_select(const float* __restrict__ x, const float* __restrict__ noise,
                         const float* __restrict__ Wr, float* __restrict__ sel) {
  int wid = (blockIdx.x * blockDim.x + threadIdx.x) >> 6;
  int lane = threadIdx.x & 63;
  if (wid >= S) return;
  const float* xr = x + (size_t)wid * M;
  float xv[8];
#pragma unroll
  for (int c = 0; c < 8; ++c) xv[c] = xr[lane + 64 * c];
  for (int e = 0; e < E; ++e) {
    const float* wr = Wr + (size_t)e * M;
    float acc = 0.f;
#pragma unroll
    for (int c = 0; c < 8; ++c) acc += xv[c] * wr[lane + 64 * c];
#pragma unroll
    for (int off = 32; off; off >>= 1) acc += __shfl_xor(acc, off);
    if (lane == 0) sel[wid * E + e] = acc + noise[wid * E + e];
  }
}

// top-2 per token + select0 (dispatch) output
__global__ void k_top2(const float* __restrict__ sel, int* __restrict__ i0, int* __restrict__ i1,
                       float* __restrict__ g0, float* __restrict__ g1, float* __restrict__ sel0) {
  int s = blockIdx.x * blockDim.x + threadIdx.x;
  if (s >= S) return;
  float v[E];
#pragma unroll
  for (int e = 0; e < E; ++e) v[e] = sel[s * E + e];
  int a0 = 0; float m0 = v[0];
#pragma unroll
  for (int e = 1; e < E; ++e) if (v[e] > m0) { m0 = v[e]; a0 = e; }
  int a1 = -1; float m1 = -3.4e38f;
#pragma unroll
  for (int e = 0; e < E; ++e) if (e != a0 && v[e] > m1) { m1 = v[e]; a1 = e; }
  i0[s] = a0; i1[s] = a1; g0[s] = m0; g1[s] = m1;
#pragma unroll
  for (int e = 0; e < E; ++e) {
    sel0[(size_t)s * (E * 2) + e * 2 + 0] = (e == a0 && m0 != 0.f) ? 1.f : 0.f;
    sel0[(size_t)s * (E * 2) + e * 2 + 1] = (e == a1 && m1 != 0.f) ? 1.f : 0.f;
  }
}

// balance_loss. Single block, deterministic.
__global__ void k_balance(const float* __restrict__ sel, const int* __restrict__ i0,
                          const int* __restrict__ i1, float* __restrict__ outb) {
  __shared__ double part[512];
  __shared__ float dpl[E];
  int t = threadIdx.x;
  int e = t & 15, r0 = t >> 4;
  double acc = 0.0;
  for (int s = r0; s < S; s += 32) acc += (double)sel[s * E + e];
  part[t] = acc;
  __syncthreads();
  for (int off = 256; off >= 16; off >>= 1) {
    if (t < off) part[t] += part[t + off];
    __syncthreads();
  }
  if (t < E) dpl[t] = (float)(part[t] / (double)S);
  __syncthreads();
  double acc2 = 0.0;
  for (int s = t; s < S; s += 512) acc2 += 0.5 * ((double)dpl[i0[s]] + (double)dpl[i1[s]]);
  part[t] = acc2;
  __syncthreads();
  for (int off = 256; off; off >>= 1) {
    if (t < off) part[t] += part[t + off];
    __syncthreads();
  }
  if (t == 0) outb[0] = (float)(part[0] / 256.0);
}

// build compact token lists per (e,k), order-preserving (deterministic)
__global__ void k_lists(const int* __restrict__ i0, const int* __restrict__ i1,
                        const float* __restrict__ g0, const float* __restrict__ g1,
                        int* __restrict__ list, int* __restrict__ cnt) {
  int ek = blockIdx.x;               // 32 blocks
  int k = ek & 1, e = ek >> 1;
  const int* route = k ? i1 : i0;
  const float* gg = k ? g1 : g0;
  __shared__ int base_s;
  __shared__ int wsum[4];
  int t = threadIdx.x;               // 256
  int lane = t & 63, w = t >> 6;
  if (t == 0) base_s = 0;
  __syncthreads();
  for (int s0 = 0; s0 < S; s0 += 256) {
    int s = s0 + t;
    bool flag = (route[s] == e) && (gg[s] != 0.f);
    unsigned long long m = __ballot(flag);
    int within = __popcll(m & ((1ull << lane) - 1ull));
    if (lane == 0) wsum[w] = __popcll(m);
    __syncthreads();
    int wbase = base_s;
    for (int i = 0; i < w; ++i) wbase += wsum[i];
    if (flag) list[ek * S + wbase + within] = s;
    __syncthreads();
    if (t == 0) base_s += wsum[0] + wsum[1] + wsum[2] + wsum[3];
    __syncthreads();
  }
  if (t == 0) cnt[ek] = base_s;
}

// expert_inputs[ek,:] = sum of x rows in list[ek] (unweighted; dispatch is 0/1)
__global__ void k_gather(const float* __restrict__ x, const int* __restrict__ list,
                         const int* __restrict__ cnt, float* __restrict__ ei) {
  int b = blockIdx.x;                // 128 = ek*4 + chunk
  int chunk = b & 3, ek = b >> 2;
  int t = threadIdx.x;               // 128
  int d = chunk * 128 + t;
  int nl = cnt[ek];
  const int* lp = list + ek * S;
  float acc = 0.f;
  int q = 0;
  for (; q + 4 <= nl; q += 4) {
    int s0 = lp[q], s1 = lp[q + 1], s2 = lp[q + 2], s3 = lp[q + 3];
    acc += x[(size_t)s0 * M + d];
    acc += x[(size_t)s1 * M + d];
    acc += x[(size_t)s2 * M + d];
    acc += x[(size_t)s3 * M + d];
  }
  for (; q < nl; ++q) acc += x[(size_t)lp[q] * M + d];
  ei[ek * M + d] = acc;
}

// generic MLP layer: wave per (e,h) output neuron, both k rows at once
template <int DIN, int HOUT, bool RELU>
__global__ void k_layer(const float* __restrict__ in, const float* __restrict__ W,
                        const float* __restrict__ bias, float* __restrict__ out) {
  int w = (blockIdx.x * blockDim.x + threadIdx.x) >> 6;
  int lane = threadIdx.x & 63;
  if (w >= E * HOUT) return;
  int e = w / HOUT, h = w - e * HOUT;
  const float* wr = W + ((size_t)e * HOUT + h) * DIN;
  const float* in0 = in + (size_t)(e * 2 + 0) * DIN;
  const float* in1 = in + (size_t)(e * 2 + 1) * DIN;
  float a0 = 0.f, a1 = 0.f;
  for (int m = lane; m < DIN; m += 64) {
    float wv = wr[m];
    a0 += wv * in0[m];
    a1 += wv * in1[m];
  }
#pragma unroll
  for (int off = 32; off; off >>= 1) {
    a0 += __shfl_xor(a0, off);
    a1 += __shfl_xor(a1, off);
  }
  if (lane == 0) {
    float bb = bias[e * HOUT + h];
    float o0 = a0 + bb, o1 = a1 + bb;
    if (RELU) { o0 = fmaxf(o0, 0.f); o1 = fmaxf(o1, 0.f); }
    out[(size_t)(e * 2 + 0) * HOUT + h] = o0;
    out[(size_t)(e * 2 + 1) * HOUT + h] = o1;
  }
}

__global__ void k_output(const float* __restrict__ eo, const int* __restrict__ i0,
                         const int* __restrict__ i1, const float* __restrict__ g0,
                         const float* __restrict__ g1, float* __restrict__ out) {
  int idx = blockIdx.x * blockDim.x + threadIdx.x;
  if (idx >= S * CC) return;
  int s = idx >> 7, d = idx & (CC - 1);
  out[idx] = g0[s] * eo[(i0[s] * 2 + 0) * CC + d] + g1[s] * eo[(i1[s] * 2 + 1) * CC + d];
}

__device__ inline unsigned short bf16_rne(float f) {
  unsigned b = __float_as_uint(f);
  return (unsigned short)((b + 0x7FFFu + ((b >> 16) & 1u)) >> 16);
}

// T rows + row sq-norms + pre-swizzled bf16 hi/lo fragment planes.
// Plane layout: idx = (((r>>5)*16 + kg)*32 + (r&31))*8 + e   (kg = k/8, e = k%8)
// -> a wave's (rowblk, ks) fragment read is 1KB fully contiguous.
__global__ void k_buildT(const float* __restrict__ eo, const int* __restrict__ idx1,
                         const int* __restrict__ idx2, const int* __restrict__ i0,
                         const int* __restrict__ i1, const float* __restrict__ g0,
                         const float* __restrict__ g1, float* __restrict__ T,
                         unsigned short* __restrict__ Phi, unsigned short* __restrict__ Plo,
                         float* __restrict__ sq, int ns, int ncnt) {
  int r = blockIdx.x, d = threadIdx.x;
  float v = 0.f;
  if (r < ns)        { int t = idx1[r];       v = g0[t] * eo[(i0[t] * 2 + 0) * CC + d]; }
  else if (r < ncnt) { int t = idx2[r - ns];  v = g1[t] * eo[(i1[t] * 2 + 1) * CC + d]; }
  T[(size_t)r * CC + d] = v;
  unsigned short hb = bf16_rne(v);
  float hf = __uint_as_float(((unsigned)hb) << 16);
  unsigned short lb = bf16_rne(v - hf);
  int pidx = (((r >> 5) * 16 + (d >> 3)) * 32 + (r & 31)) * 8 + (d & 7);
  Phi[pidx] = hb;
  Plo[pidx] = lb;
  __shared__ float red[128];
  red[d] = v * v;
  __syncthreads();
  for (int off = 64; off; off >>= 1) { if (d < off) red[d] += red[d + off]; __syncthreads(); }
  if (d == 0) sq[r] = red[0];
}

__global__ void k_colsum(const float* __restrict__ T, double* __restrict__ part, int n) {
  int d = threadIdx.x, b = blockIdx.x;
  int r0 = b * 128, r1 = min(r0 + 128, n);
  double acc = 0.0;
  for (int r = r0; r < r1; ++r) acc += (double)T[(size_t)r * CC + d];
  part[b * 128 + d] = acc;
}

__global__ void k_prep(const double* __restrict__ part, const float* __restrict__ sq,
                       float* __restrict__ cl, int n, int nblk) {
  __shared__ double red[128];
  __shared__ double csum2s;
  int d = threadIdx.x;
  double cs = 0.0;
  for (int b = 0; b < nblk; ++b) cs += part[b * 128 + d];
  red[d] = cs * cs;
  __syncthreads();
  for (int off = 64; off; off >>= 1) { if (d < off) red[d] += red[d + off]; __syncthreads(); }
  if (d == 0) csum2s = red[0];
  __syncthreads();
  double ss = 0.0;
  for (int r = d; r < n; r += 128) ss += (double)sq[r];
  red[d] = ss;
  __syncthreads();
  for (int off = 64; off; off >>= 1) { if (d < off) red[d] += red[d + off]; __syncthreads(); }
  if (d == 0) {
    double ssq = red[0];
    double nn = (double)n;
    double bwsum = 2.0 * nn * ssq - 2.0 * csum2s;
    double bw = bwsum / (nn * nn - nn) / 4.0;
#pragma unroll
    for (int l = 0; l < 5; ++l) cl[l] = (float)(1.0 / (bw * (double)(1 << l)));
  }
}

// MMD: split-bf16 MFMA (hi*hi + lo*hi + hi*lo), fragments streamed straight
// from pre-swizzled global planes (L2-resident) — no LDS staging, no barriers.
__global__ __launch_bounds__(256) void k_mmd(const unsigned short* __restrict__ Phi,
                      const unsigned short* __restrict__ Plo,
                      const float* __restrict__ sq, const float* __restrict__ cl,
                      double* __restrict__ bsum, int ns, int ncnt, int nt) {
  int L = blockIdx.x;
  int bi = 0, rem = L;
  while (rem >= nt - bi) { rem -= nt - bi; ++bi; }
  int bj = bi + rem;

  int tid = threadIdx.x;
  int lane = tid & 63, wid = tid >> 6;
  int wr = wid >> 1, wc = wid & 1;
  int lrow = lane & 31, khalf = lane >> 5;
  const int ib = bi * 128, jb = bj * 128;
  int rowoff = wr * 64, coloff = wc * 64;

  // per-rowblk(32) stride = 16 kg * 32 lanes * 8 = 4096 shorts
  size_t laneoff = (size_t)khalf * 256 + (size_t)lrow * 8;
  const unsigned short* pa_hi = Phi + (size_t)((ib + rowoff) >> 5) * 4096 + laneoff;
  const unsigned short* pa_lo = Plo + (size_t)((ib + rowoff) >> 5) * 4096 + laneoff;
  const unsigned short* pb_hi = Phi + (size_t)((jb + coloff) >> 5) * 4096 + laneoff;
  const unsigned short* pb_lo = Plo + (size_t)((jb + coloff) >> 5) * 4096 + laneoff;

  f32x16 acc[2][2];
#pragma unroll
  for (int a = 0; a < 2; ++a)
#pragma unroll
    for (int b = 0; b < 2; ++b) acc[a][b] = (f32x16)(0.f);

#pragma unroll
  for (int pass = 0; pass < 3; ++pass) {
    const unsigned short* Ap = (pass == 1) ? pa_lo : pa_hi;
    const unsigned short* Bp = (pass == 2) ? pb_lo : pb_hi;
#pragma unroll
    for (int ks = 0; ks < 8; ++ks) {
      short8 a0 = *(const short8*)(Ap + ks * 512);
      short8 a1 = *(const short8*)(Ap + 4096 + ks * 512);
      short8 b0 = *(const short8*)(Bp + ks * 512);
      short8 b1 = *(const short8*)(Bp + 4096 + ks * 512);
      acc[0][0] = __builtin_amdgcn_mfma_f32_32x32x16_bf16(a0, b0, acc[0][0], 0, 0, 0);
      acc[0][1] = __builtin_amdgcn_mfma_f32_32x32x16_bf16(a0, b1, acc[0][1], 0, 0, 0);
      acc[1][0] = __builtin_amdgcn_mfma_f32_32x32x16_bf16(a1, b0, acc[1][0], 0, 0, 0);
      acc[1][1] = __builtin_amdgcn_mfma_f32_32x32x16_bf16(a1, b1, acc[1][1], 0, 0, 0);
    }
  }

  // epilogue: d2 -> 1 exp + 4 squarings, signed sum
  float c4v = cl[4];
  float tsum = 0.f;
#pragma unroll
  for (int rb = 0; rb < 2; ++rb) {
    float sqm[16], sgm[16];
#pragma unroll
    for (int r = 0; r < 16; ++r) {
      int m = ib + rowoff + rb * 32 + ((r & 3) + 8 * (r >> 2) + 4 * khalf);
      sqm[r] = sq[m];
      sgm[r] = (m < ns) ? 1.f : (m < ncnt ? -1.f : 0.f);
    }
#pragma unroll
    for (int cb = 0; cb < 2; ++cb) {
      int nn = jb + coloff + cb * 32 + lrow;
      float sqn = sq[nn];
      float sgn = (nn < ns) ? 1.f : (nn < ncnt ? -1.f : 0.f);
      f32x16 A = acc[rb][cb];
#pragma unroll
      for (int r = 0; r < 16; ++r) {
        float d2 = sqm[r] + sqn - 2.f * A[r];
        float t = __expf(-d2 * c4v);
        float s5 = t;
        t = t * t; s5 += t;
        t = t * t; s5 += t;
        t = t * t; s5 += t;
        t = t * t; s5 += t;
        tsum += sgm[r] * sgn * s5;
      }
    }
  }
  __shared__ float rsum[256];
  rsum[tid] = tsum;
  __syncthreads();
  for (int off = 128; off; off >>= 1) {
    if (tid < off) rsum[tid] += rsum[tid + off];
    __syncthreads();
  }
  if (tid == 0) bsum[L] = (double)rsum[0] * ((bi == bj) ? 1.0 : 2.0);
}

__global__ void k_final(const double* __restrict__ bsum, int nb, int ns, float* __restrict__ outp) {
  __shared__ double red[256];
  int t = threadIdx.x;
  double acc = 0.0;
  for (int i = t; i < nb; i += 256) acc += bsum[i];
  red[t] = acc;
  __syncthreads();
  for (int off = 128; off; off >>= 1) { if (t < off) red[t] += red[t + off]; __syncthreads(); }
  if (t == 0) outp[0] = (float)(-red[0] / ((double)ns * (double)ns));
}

extern "C" void kernel_launch(void* const* d_in, const int* in_sizes, int n_in,
                              void* d_out, int out_size, void* d_ws, size_t ws_size,
                              hipStream_t stream) {
  const float* x  = (const float*)d_in[0];
  const float* noise = (const float*)d_in[1];
  const float* Wr = (const float*)d_in[2];
  const float* W1 = (const float*)d_in[3];
  const float* b1 = (const float*)d_in[4];
  const float* W2 = (const float*)d_in[5];
  const float* b2 = (const float*)d_in[6];
  const float* W3 = (const float*)d_in[7];
  const float* b3 = (const float*)d_in[8];
  const float* W4 = (const float*)d_in[9];
  const float* b4 = (const float*)d_in[10];
  const int* idx1 = (const int*)d_in[11];
  const int* idx2 = (const int*)d_in[12];
  int ns = in_sizes[11];
  int n = 2 * ns;
  int npad = (n + 127) & ~127;
  int nt = npad / 128;
  int ntri = nt * (nt + 1) / 2;
  int nblk = (n + 127) / 128;

  char* wp = (char*)d_ws;
  size_t off = 0;
  auto alloc = [&](size_t bytes) -> void* {
    void* p = wp + off;
    off += (bytes + 255) & ~(size_t)255;
    return p;
  };
  float* sel = (float*)alloc((size_t)S * E * 4);
  int*   i0  = (int*)alloc((size_t)S * 4);
  int*   i1  = (int*)alloc((size_t)S * 4);
  float* g0  = (float*)alloc((size_t)S * 4);
  float* g1  = (float*)alloc((size_t)S * 4);
  float* ei  = (float*)alloc((size_t)E * 2 * M * 4);
  int*   list = (int*)alloc((size_t)32 * S * 4);
  int*   cnt  = (int*)alloc(32 * 4);
  float* h1  = (float*)alloc((size_t)E * 2 * H1 * 4);
  float* h2  = (float*)alloc((size_t)E * 2 * H2 * 4);
  float* h3  = (float*)alloc((size_t)E * 2 * H3 * 4);
  float* eo  = (float*)alloc((size_t)E * 2 * CC * 4);
  float* T   = (float*)alloc((size_t)npad * CC * 4);
  unsigned short* Phi = (unsigned short*)alloc((size_t)npad * CC * 2);
  unsigned short* Plo = (unsigned short*)alloc((size_t)npad * CC * 2);
  float* sq  = (float*)alloc((size_t)npad * 4);
  float* cl  = (float*)alloc(8 * 4);
  double* cspart = (double*)alloc((size_t)nblk * 128 * 8);
  double* bsum   = (double*)alloc((size_t)ntri * 8);
  (void)ws_size; (void)n_in; (void)out_size;

  float* out      = (float*)d_out;
  float* out_sel0 = out + (size_t)S * CC;
  float* out_bal  = out + (size_t)S * CC + (size_t)S * E * 2;
  float* out_dist = out_bal + 1;

  k_select<<<S / 4, 256, 0, stream>>>(x, noise, Wr, sel);
  k_top2<<<S / 256, 256, 0, stream>>>(sel, i0, i1, g0, g1, out_sel0);
  k_balance<<<1, 512, 0, stream>>>(sel, i0, i1, out_bal);
  k_lists<<<32, 256, 0, stream>>>(i0, i1, g0, g1, list, cnt);
  k_gather<<<128, 128, 0, stream>>>(x, list, cnt, ei);
  k_layer<M, H1, true><<<(E * H1 + 3) / 4, 256, 0, stream>>>(ei, W1, b1, h1);
  k_layer<H1, H2, true><<<(E * H2 + 3) / 4, 256, 0, stream>>>(h1, W2, b2, h2);
  k_layer<H2, H3, true><<<(E * H3 + 3) / 4, 256, 0, stream>>>(h2, W3, b3, h3);
  k_layer<H3, CC, false><<<(E * CC + 3) / 4, 256, 0, stream>>>(h3, W4, b4, eo);
  k_output<<<(S * CC) / 256, 256, 0, stream>>>(eo, i0, i1, g0, g1, out);
  k_buildT<<<npad, 128, 0, stream>>>(eo, idx1, idx2, i0, i1, g0, g1, T, Phi, Plo, sq, ns, n);
  k_colsum<<<nblk, 128, 0, stream>>>(T, cspart, n);
  k_prep<<<1, 128, 0, stream>>>(cspart, sq, cl, n, nblk);
  k_mmd<<<ntri, 256, 0, stream>>>(Phi, Plo, sq, cl, bsum, ns, n, nt);
  k_final<<<1, 256, 0, stream>>>(bsum, ntri, ns, out_dist);
}

// Round 5
// 131.991 us; speedup vs baseline: 1.8860x; 1.8860x over previous
//
#include <hip/hip_runtime.h>

constexpr int S = 4096, M = 512, E = 16, CC = 128;
constexpr int H1 = 500, H2 = 500, H3 = 2000;

// fused: select = x@Wr^T + noise; top2; sel0 output; per-block column partials of select
__global__ void k_route(const float* __restrict__ x, const float* __restrict__ noise,
                        const float* __restrict__ Wr, int* __restrict__ i0, int* __restrict__ i1,
                        float* __restrict__ g0, float* __restrict__ g1,
                        float* __restrict__ sel0, float* __restrict__ selpart) {
  int wid = threadIdx.x >> 6, lane = threadIdx.x & 63;
  int s = blockIdx.x * 4 + wid;
  const float* xr = x + (size_t)s * M;
  float xv[8];
#pragma unroll
  for (int c = 0; c < 8; ++c) xv[c] = xr[lane + 64 * c];
  float v[E];
#pragma unroll
  for (int e = 0; e < E; ++e) {
    const float* wr = Wr + (size_t)e * M;
    float acc = 0.f;
#pragma unroll
    for (int c = 0; c < 8; ++c) acc = fmaf(xv[c], wr[lane + 64 * c], acc);
#pragma unroll
    for (int off = 32; off; off >>= 1) acc += __shfl_xor(acc, off);
    v[e] = acc + noise[s * E + e];
  }
  int a0 = 0; float m0 = v[0];
#pragma unroll
  for (int e = 1; e < E; ++e) if (v[e] > m0) { m0 = v[e]; a0 = e; }
  int a1 = -1; float m1 = -3.4e38f;
#pragma unroll
  for (int e = 0; e < E; ++e) if (e != a0 && v[e] > m1) { m1 = v[e]; a1 = e; }
  __shared__ float vsh[4][16];
  if (lane < 16) vsh[wid][lane] = v[lane];
  if (lane == 0) { i0[s] = a0; i1[s] = a1; g0[s] = m0; g1[s] = m1; }
  if (lane < 16) {
    int e = lane;
    sel0[(size_t)s * 32 + e * 2 + 0] = (e == a0 && m0 != 0.f) ? 1.f : 0.f;
    sel0[(size_t)s * 32 + e * 2 + 1] = (e == a1 && m1 != 0.f) ? 1.f : 0.f;
  }
  __syncthreads();
  if (threadIdx.x < 16) {
    int e = threadIdx.x;
    selpart[blockIdx.x * 16 + e] = vsh[0][e] + vsh[1][e] + vsh[2][e] + vsh[3][e];
  }
}

// balance_loss from column partials. Single block, deterministic.
__global__ void k_balance(const float* __restrict__ selpart, const int* __restrict__ i0,
                          const int* __restrict__ i1, float* __restrict__ outb) {
  __shared__ double part[512];
  __shared__ float dpl[E];
  int t = threadIdx.x;
  int e = t & 15, r0 = t >> 4;
  double acc = 0.0;
  for (int b = r0; b < 1024; b += 32) acc += (double)selpart[b * 16 + e];
  part[t] = acc;
  __syncthreads();
  for (int off = 256; off >= 16; off >>= 1) {
    if (t < off) part[t] += part[t + off];
    __syncthreads();
  }
  if (t < E) dpl[t] = (float)(part[t] / (double)S);
  __syncthreads();
  double acc2 = 0.0;
  for (int s = t; s < S; s += 512) acc2 += 0.5 * ((double)dpl[i0[s]] + (double)dpl[i1[s]]);
  part[t] = acc2;
  __syncthreads();
  for (int off = 256; off; off >>= 1) {
    if (t < off) part[t] += part[t + off];
    __syncthreads();
  }
  if (t == 0) outb[0] = (float)(part[0] / 256.0);
}

// compact token lists per (e,k), order-preserving (deterministic)
__global__ void k_lists(const int* __restrict__ i0, const int* __restrict__ i1,
                        const float* __restrict__ g0, const float* __restrict__ g1,
                        int* __restrict__ list, int* __restrict__ cnt) {
  int ek = blockIdx.x;
  int k = ek & 1, e = ek >> 1;
  const int* route = k ? i1 : i0;
  const float* gg = k ? g1 : g0;
  __shared__ int base_s;
  __shared__ int wsum[4];
  int t = threadIdx.x;
  int lane = t & 63, w = t >> 6;
  if (t == 0) base_s = 0;
  __syncthreads();
  for (int s0 = 0; s0 < S; s0 += 256) {
    int s = s0 + t;
    bool flag = (route[s] == e) && (gg[s] != 0.f);
    unsigned long long m = __ballot(flag);
    int within = __popcll(m & ((1ull << lane) - 1ull));
    if (lane == 0) wsum[w] = __popcll(m);
    __syncthreads();
    int wbase = base_s;
    for (int i = 0; i < w; ++i) wbase += wsum[i];
    if (flag) list[ek * S + wbase + within] = s;
    __syncthreads();
    if (t == 0) base_s += wsum[0] + wsum[1] + wsum[2] + wsum[3];
    __syncthreads();
  }
  if (t == 0) cnt[ek] = base_s;
}

// 8-way segmented gather partials (by list stride), then fixed-order reduce
__global__ void k_gather(const float* __restrict__ x, const int* __restrict__ list,
                         const int* __restrict__ cnt, float* __restrict__ gpart) {
  int b = blockIdx.x;                  // 1024 = ek(32)*chunk(4)*seg(8)
  int seg = b & 7, chunk = (b >> 3) & 3, ek = b >> 5;
  int t = threadIdx.x;                 // 128
  int d = chunk * 128 + t;
  int nl = cnt[ek];
  const int* lp = list + ek * S;
  float acc = 0.f;
  int q = seg;
  for (; q + 24 < nl; q += 32) {
    int s0 = lp[q], s1 = lp[q + 8], s2 = lp[q + 16], s3 = lp[q + 24];
    acc += x[(size_t)s0 * M + d];
    acc += x[(size_t)s1 * M + d];
    acc += x[(size_t)s2 * M + d];
    acc += x[(size_t)s3 * M + d];
  }
  for (; q < nl; q += 8) acc += x[(size_t)lp[q] * M + d];
  gpart[(size_t)seg * (32 * M) + ek * M + d] = acc;
}

__global__ void k_gather_red(const float* __restrict__ gpart, float* __restrict__ ei) {
  int idx = blockIdx.x * blockDim.x + threadIdx.x;   // 16384
  float acc = 0.f;
#pragma unroll
  for (int sg = 0; sg < 8; ++sg) acc += gpart[(size_t)sg * (32 * M) + idx];
  ei[idx] = acc;
}

// generic MLP layer: wave per (e,h) output neuron, both k rows at once
template <int DIN, int HOUT, bool RELU>
__global__ void k_layer(const float* __restrict__ in, const float* __restrict__ W,
                        const float* __restrict__ bias, float* __restrict__ out) {
  int w = (blockIdx.x * blockDim.x + threadIdx.x) >> 6;
  int lane = threadIdx.x & 63;
  if (w >= E * HOUT) return;
  int e = w / HOUT, h = w - e * HOUT;
  const float* wr = W + ((size_t)e * HOUT + h) * DIN;
  const float* in0 = in + (size_t)(e * 2 + 0) * DIN;
  const float* in1 = in + (size_t)(e * 2 + 1) * DIN;
  float a0 = 0.f, a1 = 0.f;
  for (int m = lane; m < DIN; m += 64) {
    float wv = wr[m];
    a0 += wv * in0[m];
    a1 += wv * in1[m];
  }
#pragma unroll
  for (int off = 32; off; off >>= 1) {
    a0 += __shfl_xor(a0, off);
    a1 += __shfl_xor(a1, off);
  }
  if (lane == 0) {
    float bb = bias[e * HOUT + h];
    float o0 = a0 + bb, o1 = a1 + bb;
    if (RELU) { o0 = fmaxf(o0, 0.f); o1 = fmaxf(o1, 0.f); }
    out[(size_t)(e * 2 + 0) * HOUT + h] = o0;
    out[(size_t)(e * 2 + 1) * HOUT + h] = o1;
  }
}

__global__ void k_output(const float* __restrict__ eo, const int* __restrict__ i0,
                         const int* __restrict__ i1, const float* __restrict__ g0,
                         const float* __restrict__ g1, float* __restrict__ out) {
  int idx = blockIdx.x * blockDim.x + threadIdx.x;
  if (idx >= S * CC) return;
  int s = idx >> 7, d = idx & (CC - 1);
  out[idx] = g0[s] * eo[(i0[s] * 2 + 0) * CC + d] + g1[s] * eo[(i1[s] * 2 + 1) * CC + d];
}

// 32x32 Gram of the expert-output base rows (all T rows are g * eo[ek])
__global__ void k_G(const float* __restrict__ eo, float* __restrict__ G32) {
  __shared__ float Es[32][129];
  int t = threadIdx.x;  // 256
  for (int i = t; i < 32 * 128; i += 256) Es[i >> 7][i & 127] = eo[i];
  __syncthreads();
  for (int p = t; p < 1024; p += 256) {
    int u = p >> 5, v = p & 31;
    float s = 0.f;
#pragma unroll 8
    for (int d = 0; d < 128; ++d) s = fmaf(Es[u][d], Es[v][d], s);
    G32[p] = s;
  }
}

// per-sample-row scalars: g, a = g^2*|u|^2, basis id ek
__global__ void k_rows(const int* __restrict__ idx1, const int* __restrict__ idx2,
                       const int* __restrict__ i0, const int* __restrict__ i1,
                       const float* __restrict__ g0, const float* __restrict__ g1,
                       const float* __restrict__ G32, float* __restrict__ rowg,
                       float* __restrict__ rowa, int* __restrict__ rowe,
                       int ns, int ncnt, int npad) {
  int r = blockIdx.x * 256 + threadIdx.x;
  if (r >= npad) return;
  float g = 0.f; int ek = 0;
  if (r < ns)        { int t = idx1[r];      ek = i0[t] * 2 + 0; g = g0[t]; }
  else if (r < ncnt) { int t = idx2[r - ns]; ek = i1[t] * 2 + 1; g = g1[t]; }
  rowg[r] = g;
  rowe[r] = ek;
  rowa[r] = g * g * G32[ek * 32 + ek];
}

// bw from analytic sum(d2) = 2n*sum(a) - 2*w^T G w, w[ek] = sum of g per basis
__global__ void k_prep(const float* __restrict__ rowg, const float* __restrict__ rowa,
                       const int* __restrict__ rowe, const float* __restrict__ G32,
                       float* __restrict__ cl, int ncnt) {
  __shared__ float ws[256 * 33];
  __shared__ double red[256];
  __shared__ float wfin[32];
  int t = threadIdx.x;  // 256
#pragma unroll
  for (int e = 0; e < 32; ++e) ws[t * 33 + e] = 0.f;
  double asum = 0.0;
  for (int r = t; r < ncnt; r += 256) {
    asum += (double)rowa[r];
    ws[t * 33 + rowe[r]] += rowg[r];
  }
  red[t] = asum;
  __syncthreads();
  if (t < 32) {
    float sw = 0.f;
    for (int q = 0; q < 256; ++q) sw += ws[q * 33 + t];
    wfin[t] = sw;
  }
  for (int off = 128; off; off >>= 1) { if (t < off) red[t] += red[t + off]; __syncthreads(); }
  double asum_tot = red[0];
  __syncthreads();
  double part = 0.0;
  for (int i = t; i < 1024; i += 256)
    part += (double)wfin[i >> 5] * (double)wfin[i & 31] * (double)G32[i];
  red[t] = part;
  __syncthreads();
  for (int off = 128; off; off >>= 1) { if (t < off) red[t] += red[t + off]; __syncthreads(); }
  if (t == 0) {
    double nn = (double)ncnt;
    double sumd2 = 2.0 * nn * asum_tot - 2.0 * red[0];
    double bw = sumd2 / (nn * nn - nn) / 4.0;
#pragma unroll
    for (int l = 0; l < 5; ++l) cl[l] = (float)(1.0 / (bw * (double)(1 << l)));
  }
}

// MMD tiles from row scalars only: d2 = a_i + a_j - 2 g_i g_j G[e_i][e_j]
// K2 table at stride 33 so bank = (e_i+e_j)&31; row scalars staged with 17-stride
// swizzle so the 8-row register fill is broadcast/conflict-free.
__global__ __launch_bounds__(256) void k_mmd(const float* __restrict__ rowg,
                      const float* __restrict__ rowa, const int* __restrict__ rowe,
                      const float* __restrict__ G32, const float* __restrict__ cl,
                      double* __restrict__ bsum, int ns, int ncnt, int nt) {
  int L = blockIdx.x;
  int bi = 0, rem = L;
  while (rem >= nt - bi) { rem -= nt - bi; ++bi; }
  int bj = bi + rem;
  const int ib = bi * 128, jb = bj * 128;

  __shared__ float K2[32 * 33];
  __shared__ float gAs[136], aAs[136], gBs[136], aBs[136];
  __shared__ int eAs[136], eBs[136];
  __shared__ float rsum[256];
  int tid = threadIdx.x;
  float c = cl[4];
  for (int i = tid; i < 1024; i += 256) K2[(i >> 5) * 33 + (i & 31)] = 2.f * c * G32[i];
  if (tid < 128) {
    int p = (tid & 7) * 17 + (tid >> 3);
    gAs[p] = rowg[ib + tid]; aAs[p] = c * rowa[ib + tid]; eAs[p] = rowe[ib + tid] * 33;
    gBs[p] = rowg[jb + tid]; aBs[p] = c * rowa[jb + tid]; eBs[p] = rowe[jb + tid];
  }
  __syncthreads();

  int ti = tid & 15, tj = tid >> 4;
  float gi[8], Ai[8], sgi[8], gj[8], Aj[8], sgj[8];
  int ei[8], ej[8];
#pragma unroll
  for (int r = 0; r < 8; ++r) {
    int i = ti * 8 + r, p = r * 17 + ti;
    gi[r] = gAs[p]; Ai[r] = aAs[p]; ei[r] = eAs[p];
    int m = ib + i;
    sgi[r] = (m < ns) ? 1.f : (m < ncnt ? -1.f : 0.f);
    int j = tj * 8 + r, q = r * 17 + tj;
    gj[r] = gBs[q]; Aj[r] = aBs[q]; ej[r] = eBs[q];
    int nn2 = jb + j;
    sgj[r] = (nn2 < ns) ? 1.f : (nn2 < ncnt ? -1.f : 0.f);
  }

  float tsum = 0.f;
#pragma unroll
  for (int r = 0; r < 8; ++r) {
#pragma unroll
    for (int q = 0; q < 8; ++q) {
      float gg = gi[r] * gj[q];
      float arg = fmaf(K2[ei[r] + ej[q]], gg, -(Ai[r] + Aj[q]));
      float t = __expf(arg);
      float t2 = t * t;   float s5 = t + t2;
      float t4 = t2 * t2; s5 += t4;
      float t8 = t4 * t4; s5 += t8;
      float t16 = t8 * t8; s5 += t16;
      tsum = fmaf(sgi[r] * sgj[q], s5, tsum);
    }
  }
  rsum[tid] = tsum;
  __syncthreads();
  for (int off = 128; off; off >>= 1) {
    if (tid < off) rsum[tid] += rsum[tid + off];
    __syncthreads();
  }
  if (tid == 0) bsum[L] = (double)rsum[0] * ((bi == bj) ? 1.0 : 2.0);
}

__global__ void k_final(const double* __restrict__ bsum, int nb, int ns, float* __restrict__ outp) {
  __shared__ double red[256];
  int t = threadIdx.x;
  double acc = 0.0;
  for (int i = t; i < nb; i += 256) acc += bsum[i];
  red[t] = acc;
  __syncthreads();
  for (int off = 128; off; off >>= 1) { if (t < off) red[t] += red[t + off]; __syncthreads(); }
  if (t == 0) outp[0] = (float)(-red[0] / ((double)ns * (double)ns));
}

extern "C" void kernel_launch(void* const* d_in, const int* in_sizes, int n_in,
                              void* d_out, int out_size, void* d_ws, size_t ws_size,
                              hipStream_t stream) {
  const float* x  = (const float*)d_in[0];
  const float* noise = (const float*)d_in[1];
  const float* Wr = (const float*)d_in[2];
  const float* W1 = (const float*)d_in[3];
  const float* b1 = (const float*)d_in[4];
  const float* W2 = (const float*)d_in[5];
  const float* b2 = (const float*)d_in[6];
  const float* W3 = (const float*)d_in[7];
  const float* b3 = (const float*)d_in[8];
  const float* W4 = (const float*)d_in[9];
  const float* b4 = (const float*)d_in[10];
  const int* idx1 = (const int*)d_in[11];
  const int* idx2 = (const int*)d_in[12];
  int ns = in_sizes[11];
  int n = 2 * ns;
  int npad = (n + 127) & ~127;
  int nt = npad / 128;
  int ntri = nt * (nt + 1) / 2;

  char* wp = (char*)d_ws;
  size_t off = 0;
  auto alloc = [&](size_t bytes) -> void* {
    void* p = wp + off;
    off += (bytes + 255) & ~(size_t)255;
    return p;
  };
  int*   i0  = (int*)alloc((size_t)S * 4);
  int*   i1  = (int*)alloc((size_t)S * 4);
  float* g0  = (float*)alloc((size_t)S * 4);
  float* g1  = (float*)alloc((size_t)S * 4);
  float* selpart = (float*)alloc((size_t)1024 * 16 * 4);
  int*   list = (int*)alloc((size_t)32 * S * 4);
  int*   cnt  = (int*)alloc(32 * 4);
  float* gpart = (float*)alloc((size_t)8 * 32 * M * 4);
  float* ei  = (float*)alloc((size_t)E * 2 * M * 4);
  float* h1  = (float*)alloc((size_t)E * 2 * H1 * 4);
  float* h2  = (float*)alloc((size_t)E * 2 * H2 * 4);
  float* h3  = (float*)alloc((size_t)E * 2 * H3 * 4);
  float* eo  = (float*)alloc((size_t)E * 2 * CC * 4);
  float* G32 = (float*)alloc((size_t)1024 * 4);
  float* rowg = (float*)alloc((size_t)npad * 4);
  float* rowa = (float*)alloc((size_t)npad * 4);
  int*   rowe = (int*)alloc((size_t)npad * 4);
  float* cl  = (float*)alloc(8 * 4);
  double* bsum = (double*)alloc((size_t)ntri * 8);
  (void)ws_size; (void)n_in; (void)out_size;

  float* out      = (float*)d_out;
  float* out_sel0 = out + (size_t)S * CC;
  float* out_bal  = out + (size_t)S * CC + (size_t)S * E * 2;
  float* out_dist = out_bal + 1;

  k_route<<<S / 4, 256, 0, stream>>>(x, noise, Wr, i0, i1, g0, g1, out_sel0, selpart);
  k_balance<<<1, 512, 0, stream>>>(selpart, i0, i1, out_bal);
  k_lists<<<32, 256, 0, stream>>>(i0, i1, g0, g1, list, cnt);
  k_gather<<<1024, 128, 0, stream>>>(x, list, cnt, gpart);
  k_gather_red<<<64, 256, 0, stream>>>(gpart, ei);
  k_layer<M, H1, true><<<(E * H1 + 3) / 4, 256, 0, stream>>>(ei, W1, b1, h1);
  k_layer<H1, H2, true><<<(E * H2 + 3) / 4, 256, 0, stream>>>(h1, W2, b2, h2);
  k_layer<H2, H3, true><<<(E * H3 + 3) / 4, 256, 0, stream>>>(h2, W3, b3, h3);
  k_layer<H3, CC, false><<<(E * CC + 3) / 4, 256, 0, stream>>>(h3, W4, b4, eo);
  k_output<<<(S * CC) / 256, 256, 0, stream>>>(eo, i0, i1, g0, g1, out);
  k_G<<<1, 256, 0, stream>>>(eo, G32);
  k_rows<<<(npad + 255) / 256, 256, 0, stream>>>(idx1, idx2, i0, i1, g0, g1, G32,
                                                 rowg, rowa, rowe, ns, n, npad);
  k_prep<<<1, 256, 0, stream>>>(rowg, rowa, rowe, G32, cl, n);
  k_mmd<<<ntri, 256, 0, stream>>>(rowg, rowa, rowe, G32, cl, bsum, ns, n, nt);
  k_final<<<1, 256, 0, stream>>>(bsum, ntri, ns, out_dist);
}